// Round 5
// baseline (267.654 us; speedup 1.0000x reference)
//
#include <hip/hip_runtime.h>
#include <hip/hip_bf16.h>
#include <math.h>

typedef short bf16x8 __attribute__((ext_vector_type(8)));
typedef float f32x4 __attribute__((ext_vector_type(4)));

#define N0v 120000
#define N1v 12000
#define N2v 1024
#define F_INv 602
#define KPADv 608
#define HCv 64
#define NCLSv 41
#define NEGv 0.2f

__device__ __forceinline__ float b2f(unsigned short u) {
  return __uint_as_float(((unsigned int)u) << 16);
}
__device__ __forceinline__ unsigned short f2b(float f) {
  unsigned int u = __float_as_uint(f);
  u += 0x7fffu + ((u >> 16) & 1u);
  return (unsigned short)(u >> 16);
}
__device__ __forceinline__ unsigned int pk2(float lo, float hi) {
  __hip_bfloat162 h = __float22bfloat162_rn(make_float2(lo, hi));
  unsigned int u;
  __builtin_memcpy(&u, &h, 4);
  return u;
}
__device__ __forceinline__ float leaky(float v) {
  return v > 0.f ? v : NEGv * v;
}

// ---------------- prep: W1 transpose+convert to Wt[64][608] bf16, zero deg arrays ----------------
__global__ void k_prep(const float* __restrict__ W1, unsigned short* __restrict__ Wt,
                       int* __restrict__ deg1, int* __restrict__ deg2) {
  int idx = blockIdx.x * 256 + threadIdx.x;
  if (idx < HCv * KPADv) {
    int n = idx / KPADv, k = idx % KPADv;
    Wt[idx] = (k < F_INv) ? f2b(W1[k * HCv + n]) : (unsigned short)0;
  }
  if (idx < N1v) deg1[idx] = 0;
  if (idx < N2v) deg2[idx] = 0;
}

// ---------------- GEMM v5: H = x @ W1 + fused att dots ----------------
// A: LDS-staged per K-tile (async-split: issue loads early, write after compute+barrier).
// B: LDS, two K-halves. 78.5KB LDS -> 2 blocks/CU (16 waves).
__global__ __launch_bounds__(512, 4) void k_gemm1(const float* __restrict__ x,
                                                  const unsigned short* __restrict__ Wt,
                                                  unsigned short* __restrict__ H,
                                                  float* __restrict__ as1,
                                                  float* __restrict__ ad1,
                                                  const float* __restrict__ att_s,
                                                  const float* __restrict__ att_d) {
  __shared__ unsigned short As[128][136];  // stride 68 dw === 4 (mod 32): uniform banks
  __shared__ unsigned short Bs[64][352];   // stride 176 dw === 16 (mod 32): uniform banks
  __shared__ float sAtt[128];
  const int tid = threadIdx.x;
  const int wave = tid >> 6, lane = tid & 63;
  const int c15 = lane & 15, kseg = lane >> 4;
  const int block_row = blockIdx.x * 128;
  const int r = tid >> 2, c = tid & 3;  // staging: 4 threads per row
  const float* rowp = x + (size_t)min(block_row + r, N0v - 1) * F_INv;

  if (tid < 128) sAtt[tid] = (tid < 64) ? att_s[tid] : att_d[tid - 64];

  float fa[32];
  // full tile t1 (width 128 floats at K0=t1*128): thread covers floats c*32..c*32+31
  auto loadA_full = [&](int t1) {
    const float* p = rowp + t1 * 128 + c * 32;
#pragma unroll
    for (int q = 0; q < 16; ++q) {
      float2 v = *reinterpret_cast<const float2*>(p + 2 * q);
      fa[2 * q] = v.x;
      fa[2 * q + 1] = v.y;
    }
  };
  // tail tile (floats 512..607, width 96): thread covers 512+c*24 .. +23, zero pad >=602
  auto loadA_tail = [&]() {
    const int base = 512 + c * 24;
#pragma unroll
    for (int q = 0; q < 12; ++q) {
      int fidx = base + 2 * q;
      if (fidx + 2 <= F_INv) {
        float2 v = *reinterpret_cast<const float2*>(rowp + fidx);
        fa[2 * q] = v.x;
        fa[2 * q + 1] = v.y;
      } else {
        fa[2 * q] = 0.f;
        fa[2 * q + 1] = 0.f;
      }
    }
  };
  auto writeA_full = [&]() {
#pragma unroll
    for (int q = 0; q < 4; ++q) {
      uint4 u = make_uint4(pk2(fa[8 * q + 0], fa[8 * q + 1]), pk2(fa[8 * q + 2], fa[8 * q + 3]),
                           pk2(fa[8 * q + 4], fa[8 * q + 5]), pk2(fa[8 * q + 6], fa[8 * q + 7]));
      *reinterpret_cast<uint4*>(&As[r][c * 32 + q * 8]) = u;
    }
  };
  auto writeA_tail = [&]() {
#pragma unroll
    for (int q = 0; q < 3; ++q) {
      uint4 u = make_uint4(pk2(fa[8 * q + 0], fa[8 * q + 1]), pk2(fa[8 * q + 2], fa[8 * q + 3]),
                           pk2(fa[8 * q + 4], fa[8 * q + 5]), pk2(fa[8 * q + 6], fa[8 * q + 7]));
      *reinterpret_cast<uint4*>(&As[r][c * 24 + q * 8]) = u;
    }
  };
  auto stageB = [&](int kofs, int nkt) {  // Wt[:, kofs : kofs + nkt*32] -> Bs[:, 0 : nkt*32]
    const int w = nkt * 4;                // 16B chunks per row
    for (int i = tid; i < 64 * w; i += 512) {
      int rr = i / w, cc = (i % w) * 8;
      *reinterpret_cast<uint4*>(&Bs[rr][cc]) =
          *reinterpret_cast<const uint4*>(Wt + (size_t)rr * KPADv + kofs + cc);
    }
  };

  f32x4 acc[4];
#pragma unroll
  for (int n = 0; n < 4; ++n) acc[n] = (f32x4){0.f, 0.f, 0.f, 0.f};

  loadA_full(0);  // issue HBM loads first
  stageB(0, 8);   // B half0: kt 0..7 (k 0..255)
  writeA_full();  // implicit vmcnt wait
  __syncthreads();

#pragma unroll
  for (int t = 0; t < 5; ++t) {
    // early-issue next tile's A loads (hidden under compute + write window)
    if (t < 3) loadA_full(t + 1);
    else if (t == 3) loadA_tail();

    const int TKT = (t < 4) ? 4 : 3;
#pragma unroll
    for (int ktl = 0; ktl < 4; ++ktl) {
      if (ktl < TKT) {
        const int kt = t * 4 + ktl;
        bf16x8 a = *reinterpret_cast<const bf16x8*>(&As[wave * 16 + c15][ktl * 32 + kseg * 8]);
        const int bk = (kt < 8 ? kt * 32 : (kt - 8) * 32) + kseg * 8;
#pragma unroll
        for (int n = 0; n < 4; ++n) {
          bf16x8 b = *reinterpret_cast<const bf16x8*>(&Bs[n * 16 + c15][bk]);
          acc[n] = __builtin_amdgcn_mfma_f32_16x16x32_bf16(a, b, acc[n], 0, 0, 0);
        }
      }
    }
    __syncthreads();               // LDS reads of tile t done
    if (t == 1) stageB(256, 11);   // B half1: kt 8..18 (k 256..607)
    if (t < 3) writeA_full();
    else if (t == 3) writeA_tail();
    __syncthreads();               // staging visible before next compute
  }

  // epilogue: col = n*16 + c15, row = wave*16 + kseg*4 + j; fused att dots
  float attS[4], attD[4];
#pragma unroll
  for (int n = 0; n < 4; ++n) {
    attS[n] = sAtt[n * 16 + c15];
    attD[n] = sAtt[64 + n * 16 + c15];
  }
#pragma unroll
  for (int j = 0; j < 4; ++j) {
    int row = block_row + wave * 16 + kseg * 4 + j;
    bool rok = row < N0v;
#pragma unroll
    for (int n = 0; n < 4; ++n) {
      if (rok) H[(size_t)row * HCv + n * 16 + c15] = f2b(acc[n][j]);
      float ps = acc[n][j] * attS[n];
      float pd = acc[n][j] * attD[n];
      ps += __shfl_xor(ps, 1, 64);
      ps += __shfl_xor(ps, 2, 64);
      ps += __shfl_xor(ps, 4, 64);
      pd += __shfl_xor(pd, 1, 64);
      pd += __shfl_xor(pd, 2, 64);
      pd += __shfl_xor(pd, 4, 64);
      if (rok && ((c15 & 7) == 0)) {
        int hd = n * 2 + (c15 >> 3);
        as1[(size_t)row * 8 + hd] = ps;
        if (row < N1v) ad1[(size_t)row * 8 + hd] = pd;
      }
    }
  }
}

// ---------------- merged CSR build (both graphs) ----------------
__global__ void k_count2x(const int* __restrict__ dst1, int E1, int* __restrict__ deg1,
                          const int* __restrict__ dst2, int E2, int* __restrict__ deg2) {
  int e = blockIdx.x * 256 + threadIdx.x;
  if (e < E1) atomicAdd(&deg1[dst1[e]], 1);
  if (e < E2) atomicAdd(&deg2[dst2[e]], 1);
}

template <int ELT>
__device__ __forceinline__ void scan_body(const int* __restrict__ deg, int* __restrict__ rs,
                                          int* __restrict__ cur, int n) {
  __shared__ int wsum[16];
  const int t = threadIdx.x, lane = t & 63, wid = t >> 6;
  int vals[ELT];
  int tot = 0;
#pragma unroll
  for (int e = 0; e < ELT; ++e) {
    int i = t * ELT + e;
    int v = (i < n) ? deg[i] : 0;
    vals[e] = v;
    tot += v;
  }
  int s = tot;
#pragma unroll
  for (int off = 1; off < 64; off <<= 1) {
    int u = __shfl_up(s, off, 64);
    if (lane >= off) s += u;
  }
  if (lane == 63) wsum[wid] = s;
  __syncthreads();
  if (t < 16) {
    int w = wsum[t];
#pragma unroll
    for (int off = 1; off < 16; off <<= 1) {
      int u = __shfl_up(w, off, 64);
      if (t >= off) w += u;
    }
    wsum[t] = w;
  }
  __syncthreads();
  int woff = (wid == 0) ? 0 : wsum[wid - 1];
  int run = woff + s - tot;
#pragma unroll
  for (int e = 0; e < ELT; ++e) {
    int i = t * ELT + e;
    if (i < n) {
      rs[i] = run;
      cur[i] = run;
    }
    run += vals[e];
  }
  if (t == 1023) rs[n] = run;
}

__global__ __launch_bounds__(1024) void k_scan2x(const int* __restrict__ deg1, int* __restrict__ rs1,
                                                 int* __restrict__ cur1, int n1,
                                                 const int* __restrict__ deg2, int* __restrict__ rs2,
                                                 int* __restrict__ cur2, int n2) {
  if (blockIdx.x == 0)
    scan_body<12>(deg1, rs1, cur1, n1);
  else
    scan_body<12>(deg2, rs2, cur2, n2);
}

__global__ void k_scatter2x(const int* __restrict__ src1, const int* __restrict__ dst1, int E1,
                            int* __restrict__ cur1, int* __restrict__ es1,
                            const int* __restrict__ src2, const int* __restrict__ dst2, int E2,
                            int* __restrict__ cur2, int* __restrict__ es2) {
  int e = blockIdx.x * 256 + threadIdx.x;
  if (e < E1) {
    int p = atomicAdd(&cur1[dst1[e]], 1);
    es1[p] = src1[e];
  }
  if (e < E2) {
    int p = atomicAdd(&cur2[dst2[e]], 1);
    es2[p] = src2[e];
  }
}

// ---------------- layer-1 attention: one wave per dst, online softmax ----------------
__global__ __launch_bounds__(256) void k_attn1(const float* __restrict__ as1,
                                               const float* __restrict__ ad1,
                                               const int* __restrict__ rs,
                                               const int* __restrict__ esrc,
                                               const unsigned short* __restrict__ H,
                                               const float* __restrict__ b1,
                                               float* __restrict__ h1) {
  int wave = threadIdx.x >> 6, lane = threadIdx.x & 63;
  int d = blockIdx.x * 4 + wave;
  if (d >= N1v) return;
  int h = lane >> 3;
  int beg = rs[d], end = rs[d + 1];
  float adh = ad1[(size_t)d * 8 + h];
  float m = leaky(as1[(size_t)d * 8 + h] + adh);  // self-loop term, e=1
  float ssum = 1.f;
  float acc = b2f(H[(size_t)d * HCv + lane]);
  for (int p = beg; p < end; ++p) {
    int s = esrc[p];
    float a = leaky(as1[(size_t)s * 8 + h] + adh);
    float hv = b2f(H[(size_t)s * HCv + lane]);
    float mn = fmaxf(m, a);
    float sc = __expf(m - mn);
    float e = __expf(a - mn);
    ssum = ssum * sc + e;
    acc = acc * sc + e * hv;
    m = mn;
  }
  float o = acc / ssum + b1[lane];
  o = o > 0.f ? o : expm1f(o);  // ELU
  h1[(size_t)d * HCv + lane] = o;
}

// ---------------- layer-2 features: g = h1 @ W2, + attention dots ----------------
__global__ __launch_bounds__(256) void k_l2feat(const float* __restrict__ h1,
                                                const float* __restrict__ W2,
                                                const float* __restrict__ a_s,
                                                const float* __restrict__ a_d,
                                                float* __restrict__ g,
                                                float* __restrict__ as2,
                                                float* __restrict__ ad2) {
  __shared__ float w[64 * 41];
  __shared__ float vs[41], vd[41];
  int tid = threadIdx.x;
  for (int idx = tid; idx < 64 * 41; idx += 256) w[idx] = W2[idx];
  if (tid < 41) {
    vs[tid] = a_s[tid];
    vd[tid] = a_d[tid];
  }
  __syncthreads();
  int i = blockIdx.x * 256 + tid;
  if (i >= N1v) return;
  float r[64];
  const float4* hp = reinterpret_cast<const float4*>(h1 + (size_t)i * HCv);
#pragma unroll
  for (int q = 0; q < 16; ++q) {
    float4 t = hp[q];
    r[q * 4 + 0] = t.x; r[q * 4 + 1] = t.y; r[q * 4 + 2] = t.z; r[q * 4 + 3] = t.w;
  }
  float sa = 0.f, da = 0.f;
  for (int c = 0; c < 41; ++c) {
    float a = 0.f;
#pragma unroll
    for (int k = 0; k < 64; ++k) a += r[k] * w[k * 41 + c];
    g[(size_t)i * 41 + c] = a;
    sa += a * vs[c];
    da += a * vd[c];
  }
  as2[i] = sa;
  ad2[i] = da;
}

// ---------------- layer-2 attention + log_softmax ----------------
__global__ __launch_bounds__(256) void k_attn2(const float* __restrict__ as2,
                                               const float* __restrict__ ad2,
                                               const int* __restrict__ rs,
                                               const int* __restrict__ esrc,
                                               const float* __restrict__ g,
                                               const float* __restrict__ b2,
                                               float* __restrict__ out) {
  int wave = threadIdx.x >> 6, lane = threadIdx.x & 63;
  int d = blockIdx.x * 4 + wave;
  if (d >= N2v) return;
  int beg = rs[d], end = rs[d + 1];
  float ad = ad2[d];
  float a_self = leaky(as2[d] + ad);
  float m = a_self;
  for (int p = beg; p < end; ++p) m = fmaxf(m, leaky(as2[esrc[p]] + ad));
  float ssum, acc;
  {
    float e = __expf(a_self - m);
    ssum = e;
    acc = (lane < 41) ? e * g[(size_t)d * 41 + lane] : 0.f;
  }
  for (int p = beg; p < end; ++p) {
    int s = esrc[p];
    float e = __expf(leaky(as2[s] + ad) - m);
    ssum += e;
    if (lane < 41) acc += e * g[(size_t)s * 41 + lane];
  }
  float logit = acc / ssum + ((lane < 41) ? b2[lane] : 0.f);
  float v = (lane < 41) ? logit : -INFINITY;
  float mx = v;
#pragma unroll
  for (int o = 32; o >= 1; o >>= 1) mx = fmaxf(mx, __shfl_xor(mx, o, 64));
  float p = (lane < 41) ? __expf(v - mx) : 0.f;
  float sum = p;
#pragma unroll
  for (int o = 32; o >= 1; o >>= 1) sum += __shfl_xor(sum, o, 64);
  if (lane < 41) out[(size_t)d * 41 + lane] = v - mx - logf(sum);
}

// ---------------- host launch ----------------
extern "C" void kernel_launch(void* const* d_in, const int* in_sizes, int n_in,
                              void* d_out, int out_size, void* d_ws, size_t ws_size,
                              hipStream_t stream) {
  const float* x = (const float*)d_in[0];
  const int* ei1 = (const int*)d_in[1];
  const int* ei2 = (const int*)d_in[2];
  const float* W1 = (const float*)d_in[5];
  const float* att_src1 = (const float*)d_in[6];
  const float* att_dst1 = (const float*)d_in[7];
  const float* b1 = (const float*)d_in[8];
  const float* W2 = (const float*)d_in[9];
  const float* att_src2 = (const float*)d_in[10];
  const float* att_dst2 = (const float*)d_in[11];
  const float* b2 = (const float*)d_in[12];
  float* out = (float*)d_out;

  const int E1 = in_sizes[1] / 2;
  const int E2 = in_sizes[2] / 2;
  const int* src1 = ei1;
  const int* dst1 = ei1 + E1;
  const int* src2 = ei2;
  const int* dst2 = ei2 + E2;

  char* w = (char*)d_ws;
  size_t off = 0;
  auto alloc = [&](size_t bytes) {
    void* p = w + off;
    off += (bytes + 255) & ~(size_t)255;
    return p;
  };
  unsigned short* Wt  = (unsigned short*)alloc((size_t)HCv * KPADv * 2);
  unsigned short* H   = (unsigned short*)alloc((size_t)N0v * HCv * 2);
  float* as1 = (float*)alloc((size_t)N0v * 8 * 4);
  float* ad1 = (float*)alloc((size_t)N1v * 8 * 4);
  int* deg1  = (int*)alloc((size_t)N1v * 4);
  int* rs1   = (int*)alloc((size_t)(N1v + 1) * 4);
  int* cur1  = (int*)alloc((size_t)N1v * 4);
  int* es1   = (int*)alloc((size_t)E1 * 4);
  float* h1  = (float*)alloc((size_t)N1v * HCv * 4);
  float* g   = (float*)alloc((size_t)N1v * 41 * 4);
  float* as2 = (float*)alloc((size_t)N1v * 4);
  float* ad2 = (float*)alloc((size_t)N1v * 4);
  int* deg2  = (int*)alloc((size_t)N2v * 4);
  int* rs2   = (int*)alloc((size_t)(N2v + 1) * 4);
  int* cur2  = (int*)alloc((size_t)N2v * 4);
  int* es2   = (int*)alloc((size_t)E2 * 4);
  (void)ws_size; (void)n_in; (void)out_size;

  k_prep<<<(HCv * KPADv + 255) / 256, 256, 0, stream>>>(W1, Wt, deg1, deg2);
  k_gemm1<<<(N0v + 127) / 128, 512, 0, stream>>>(x, Wt, H, as1, ad1, att_src1, att_dst1);

  k_count2x<<<(E1 + 255) / 256, 256, 0, stream>>>(dst1, E1, deg1, dst2, E2, deg2);
  k_scan2x<<<2, 1024, 0, stream>>>(deg1, rs1, cur1, N1v, deg2, rs2, cur2, N2v);
  k_scatter2x<<<(E1 + 255) / 256, 256, 0, stream>>>(src1, dst1, E1, cur1, es1,
                                                    src2, dst2, E2, cur2, es2);
  k_attn1<<<N1v / 4, 256, 0, stream>>>(as1, ad1, rs1, es1, H, b1, h1);
  k_l2feat<<<(N1v + 255) / 256, 256, 0, stream>>>(h1, W2, att_src2, att_dst2, g, as2, ad2);
  k_attn2<<<N2v / 4, 256, 0, stream>>>(as2, ad2, rs2, es2, g, b2, out);
}